// Round 5
// baseline (274.967 us; speedup 1.0000x reference)
//
#include <hip/hip_runtime.h>
#include <hip/hip_bf16.h>
#include <cstdint>
#include <cstddef>

#define M_DIM 8192
#define K_DIM 4096
#define N_DIM 4096

typedef __bf16 bf16x8 __attribute__((ext_vector_type(8)));
typedef float  f32x4  __attribute__((ext_vector_type(4)));

__device__ __forceinline__ unsigned short f32_to_bf16_rne(float f) {
  unsigned int u = __builtin_bit_cast(unsigned int, f);
  u += 0x7FFFu + ((u >> 16) & 1u);
  return (unsigned short)(u >> 16);
}

// Single fused fp32->bf16 conversion for both A and W (one launch).
__global__ void __launch_bounds__(256) cvt_both(const float* __restrict__ A,
                                                const float* __restrict__ W,
                                                unsigned short* __restrict__ Abf,
                                                unsigned short* __restrict__ Wbf,
                                                int a4, int tot4) {
  int i = blockIdx.x * blockDim.x + threadIdx.x;
  int stride = gridDim.x * blockDim.x;
  for (; i < tot4; i += stride) {
    const float4* s = (i < a4) ? &reinterpret_cast<const float4*>(A)[i]
                               : &reinterpret_cast<const float4*>(W)[i - a4];
    ushort4* d = (i < a4) ? &reinterpret_cast<ushort4*>(Abf)[i]
                          : &reinterpret_cast<ushort4*>(Wbf)[i - a4];
    float4 v = *s;
    ushort4 o;
    o.x = f32_to_bf16_rne(v.x);
    o.y = f32_to_bf16_rne(v.y);
    o.z = f32_to_bf16_rne(v.z);
    o.w = f32_to_bf16_rne(v.w);
    *d = o;
  }
}

__device__ __forceinline__ void gload16(const void* g, void* l) {
  __builtin_amdgcn_global_load_lds((const __attribute__((address_space(1))) void*)g,
                                   (__attribute__((address_space(3))) void*)l, 16, 0, 0);
}

// 256x256-tile, BK=64, 8-wave (2Mx4N), 8-phase pipelined GEMM.
//
// ROUND-5 CHANGES vs round 4 (evidence: MfmaUtil 54.6, VALUBusy 21, ~24% wait):
//  1. Hoisted ds_read bases. Since row&7 == fr&7 for all fragment rows (every
//     non-fr row term is a multiple of 8), the swizzle XOR operand is
//     per-thread constant and the low bits low[k2] = ((k2<<6)|(ko<<4)) ^
//     ((fr&7)<<4) are loop-invariant. 8 base pointers (A/B x bb x k2); every
//     inner ds_read is base + compile-time immediate -> zero per-iter VALU
//     for LDS addressing.
//  2. Stage slots shifted one phase earlier; both vmcnt gates relax
//     VM(4) -> VM(6), issue-to-wait slack >= 3 phases (~1900cy > L3/HBM
//     latency), so waves stop camping on vmcnt.
//
// Invariant used throughout: every ds_read in phase p feeds an MFMA in phase
// p, and the compiler's counted lgkmcnt wait precedes that MFMA, which
// precedes the phase-end s_barrier -> a wave crossing a barrier has ALL its
// fragment reads complete. Hence a stage-write placed >=1 phase after a
// region's last collective read cannot race it (WAR-safe).
//
// Collective read map (wm in {0,1} means LDA8 touches BOTH A halves; wn in
// {0..3} means LDB4 touches BOTH B halves):
//   buf0.B last read end-ph2 | buf0.A end-ph3 | buf1.B end-ph6 | buf1.A end-ph7
// Stage slots (steady iter, kb=2i):
//   ph1: b1.A1<-kb+1   ph3: b0.B0<-kb+2   ph4: b0.B1,b0.A0<-kb+2
//   ph5: b0.A1<-kb+2   ph7: b1.B0<-kb+3   ph8: b1.B1,b1.A0<-kb+3
// Each is >=1 phase after its region's last read (ph1 ok: buf1.A last read
// prev ph7, two barriers between; ph4 ok: ph4 reads nothing; ph8 ok: ditto).
// In-flight landings only touch regions not being read in their window.
//
// vmcnt audit (2 loads/STAGE, in-order retire, per-wave):
//   end-ph4: outstanding = prev-ph7(2) + prev-ph8(4) + ph1(2) + ph3(2) +
//            ph4(4) = 14; need oldest 8 (= all of buf1 kb+1) -> VM(6).
//   end-ph8: outstanding = ph3(2)+ph4(4)+ph5(2)+ph7(2)+ph8(4) = 14; need
//            oldest 8 (= all of buf0 kb+2) -> VM(6).
//   Youngest gated load issued >= 3 phases before its gate. Never vmcnt(0)
//   in steady state (T4).
__global__ void __launch_bounds__(512, 2)
gemm256_8ph(const __bf16* __restrict__ A, const __bf16* __restrict__ W,
            const float* __restrict__ bias, float* __restrict__ out) {
  __shared__ __align__(16) char lds[131072];

  const int tid  = threadIdx.x;
  const int wave = tid >> 6, lane = tid & 63;
  const int wm = wave >> 2, wn = wave & 3;   // 2 x 4 wave grid, each owns 128x64
  const int fr = lane & 15, ko = lane >> 4;

  // Bijective XCD swizzle (512 % 8 == 0): XCD x gets 64 consecutive swzids =
  // 2 B-panels (4 MB = its L2).
  const int swzid = ((blockIdx.x & 7) << 6) + (blockIdx.x >> 3);
  const int bm = swzid & 31, bn = swzid >> 5;
  const int brow = bm << 8, bcol = bn << 8;

  // Staging: half-tile = 128 rows x 64 k (16 KiB), 512 threads x 2 gload16.
  // T2 swizzle: LDS 16B-chunk (row, j) holds global k-chunk j ^ (row&7),
  // via pre-swizzled global source + linear (wave-uniform) LDS dest.
  const int r0 = tid >> 3;
  const int jc = (((tid & 7) ^ (r0 & 7)) << 4);
  const char* aSrc = (const char*)A + (size_t)(brow + r0) * (K_DIM * 2) + jc;
  const char* bSrc = (const char*)W + (size_t)(bcol + r0) * (K_DIM * 2) + jc;
  char* dstW = lds + (wave << 10);  // wave-uniform LDS base

#define STAGE(ms, h, bb, kt) do {                                              \
    const char* s_ = ((ms) ? bSrc : aSrc)                                      \
        + (size_t)(h) * (128ull * K_DIM * 2) + (size_t)(kt) * 128;             \
    char* d_ = dstW + (bb) * 65536 + (ms) * 32768 + (h) * 16384;               \
    gload16(s_, d_);                                                           \
    gload16(s_ + 64ull * K_DIM * 2, d_ + 8192);                                \
  } while (0)

  // Hoisted ds_read bases. Logical address of A frag (row ra, k2, ko):
  //   (ra<<7) + [((k2<<6)|(ko<<4)) ^ ((ra&7)<<4)]  with ra&7 == fr&7.
  // low[k2] is per-thread constant; (mh<<13)+(ml<<11) is a compile-time
  // immediate on the ds_read.
  const int low0 = (ko << 4) ^ ((fr & 7) << 4);
  const int low1 = low0 ^ 64;
  const char* baA[2][2];  // [bb][k2] -- constant-indexed only (SROA-safe)
  const char* baB[2][2];
  baA[0][0] = lds + (wm << 14) + (fr << 7) + low0;
  baA[0][1] = lds + (wm << 14) + (fr << 7) + low1;
  baA[1][0] = baA[0][0] + 65536;
  baA[1][1] = baA[0][1] + 65536;
  baB[0][0] = lds + 32768 + (wn << 13) + (fr << 7) + low0;
  baB[0][1] = lds + 32768 + (wn << 13) + (fr << 7) + low1;
  baB[1][0] = baB[0][0] + 65536;
  baB[1][1] = baB[0][1] + 65536;

  bf16x8 a[4][2];   // current m-half fragments (4 m-frags x 2 k-steps)
  bf16x8 b[4][2];   // 4 n-frags x 2 k-steps
  f32x4 acc[8][4] = {};

#define LDA8(bb, mh) do {                                                      \
    _Pragma("unroll") for (int ml = 0; ml < 4; ++ml) {                         \
      a[ml][0] = *(const bf16x8*)(baA[bb][0] + ((mh) << 13) + (ml << 11));     \
      a[ml][1] = *(const bf16x8*)(baA[bb][1] + ((mh) << 13) + (ml << 11)); }   \
  } while (0)

#define LDB4(bb, nh) do {                                                      \
    _Pragma("unroll") for (int nl = 0; nl < 2; ++nl) {                         \
      b[(nh) * 2 + nl][0] = *(const bf16x8*)(baB[bb][0] + ((nh) << 12) + (nl << 11)); \
      b[(nh) * 2 + nl][1] = *(const bf16x8*)(baB[bb][1] + ((nh) << 12) + (nl << 11)); } \
  } while (0)

#define MFMAQ(mh, nh) do {                                                     \
    __builtin_amdgcn_s_setprio(1);                                             \
    _Pragma("unroll") for (int ml = 0; ml < 4; ++ml)                           \
    _Pragma("unroll") for (int nl = 0; nl < 2; ++nl)                           \
    _Pragma("unroll") for (int k2 = 0; k2 < 2; ++k2)                           \
      acc[(mh) * 4 + ml][(nh) * 2 + nl] = __builtin_amdgcn_mfma_f32_16x16x32_bf16( \
          a[ml][k2], b[(nh) * 2 + nl][k2], acc[(mh) * 4 + ml][(nh) * 2 + nl], 0, 0, 0); \
    __builtin_amdgcn_s_setprio(0);                                             \
  } while (0)

#define BAR() __builtin_amdgcn_s_barrier()
#define VM(n) asm volatile("s_waitcnt vmcnt(" #n ")" ::: "memory")

  // Prologue: buf0 <- k0 (4 halves), buf1 <- k1 (B0,B1,A0). 14 outstanding;
  // VM(6) -> oldest 8 (= all of buf0 k0) landed. b1.A1 staged at iter-0 ph1.
  STAGE(1, 0, 0, 0);
  STAGE(1, 1, 0, 0);
  STAGE(0, 0, 0, 0);
  STAGE(0, 1, 0, 0);
  STAGE(1, 0, 1, 1);
  STAGE(1, 1, 1, 1);
  STAGE(0, 0, 1, 1);
  VM(6);
  BAR();

  for (int i = 0; i < 31; ++i) {
    const int kb = 2 * i;
    // ph1: Q(0,0) on buf0 | stage b1.A1 <- kb+1
    LDA8(0, 0); LDB4(0, 0); STAGE(0, 1, 1, kb + 1);
    MFMAQ(0, 0); BAR();
    // ph2: Q(0,1)
    LDB4(0, 1);
    MFMAQ(0, 1); BAR();
    // ph3: Q(1,1) | stage b0.B0 <- kb+2
    LDA8(0, 1); STAGE(1, 0, 0, kb + 2);
    MFMAQ(1, 1); BAR();
    // ph4: Q(1,0) | stage b0.B1, b0.A0 <- kb+2 | VM(6): buf1(kb+1) landed
    STAGE(1, 1, 0, kb + 2); STAGE(0, 0, 0, kb + 2);
    MFMAQ(1, 0); VM(6); BAR();
    // ph5: Q(0,0) on buf1 | stage b0.A1 <- kb+2
    LDA8(1, 0); LDB4(1, 0); STAGE(0, 1, 0, kb + 2);
    MFMAQ(0, 0); BAR();
    // ph6: Q(0,1)
    LDB4(1, 1);
    MFMAQ(0, 1); BAR();
    // ph7: Q(1,1) | stage b1.B0 <- kb+3
    LDA8(1, 1); STAGE(1, 0, 1, kb + 3);
    MFMAQ(1, 1); BAR();
    // ph8: Q(1,0) | stage b1.B1, b1.A0 <- kb+3 | VM(6): buf0(kb+2) landed
    STAGE(1, 1, 1, kb + 3); STAGE(0, 0, 1, kb + 3);
    MFMAQ(1, 0); VM(6); BAR();
  }

  // Peel (kb=62): stage only b1.A1 <- k63 at ph1; VM(0) at ph4 drains the
  // 8 outstanding (prev ph7: 2, prev ph8: 4, ph1: 2) = all of buf1 k63.
  LDA8(0, 0); LDB4(0, 0); STAGE(0, 1, 1, 63);
  MFMAQ(0, 0); BAR();
  LDB4(0, 1);
  MFMAQ(0, 1); BAR();
  LDA8(0, 1);
  MFMAQ(1, 1); BAR();
  MFMAQ(1, 0); VM(0); BAR();
  LDA8(1, 0); LDB4(1, 0);
  MFMAQ(0, 0); BAR();
  LDB4(1, 1);
  MFMAQ(0, 1); BAR();
  LDA8(1, 1);
  MFMAQ(1, 1); BAR();
  MFMAQ(1, 0);

  // Epilogue: C/D mapping col=lane&15, row=(lane>>4)*4+j (m89-verified), + bias.
  const int oc0 = bcol + (wn << 6) + fr;
  const int or0 = brow + (wm << 7) + (ko << 2);
  float bv[4];
#pragma unroll
  for (int nl = 0; nl < 4; ++nl) bv[nl] = bias[oc0 + nl * 16];
#pragma unroll
  for (int ml = 0; ml < 8; ++ml)
#pragma unroll
    for (int nl = 0; nl < 4; ++nl)
#pragma unroll
      for (int j = 0; j < 4; ++j)
        out[(size_t)(or0 + ml * 16 + j) * N_DIM + (oc0 + nl * 16)] =
            acc[ml][nl][j] + bv[nl];

#undef STAGE
#undef LDA8
#undef LDB4
#undef MFMAQ
#undef BAR
#undef VM
}

// Safety net if d_ws is too small for bf16 copies of A and W: correct but slow.
__global__ void naive_linear(const float* __restrict__ A, const float* __restrict__ W,
                             const float* __restrict__ bias, float* __restrict__ out) {
  int n = blockIdx.y;
  int o = blockIdx.x * 256 + threadIdx.x;
  const float* a = A + (size_t)n * K_DIM;
  const float* w = W + (size_t)o * K_DIM;
  float acc = 0.f;
  for (int k = 0; k < K_DIM; ++k) acc += a[k] * w[k];
  out[(size_t)n * N_DIM + o] = acc + bias[o];
}

extern "C" void kernel_launch(void* const* d_in, const int* in_sizes, int n_in,
                              void* d_out, int out_size, void* d_ws, size_t ws_size,
                              hipStream_t stream) {
  const float* A    = (const float*)d_in[0];
  const float* W    = (const float*)d_in[1];
  const float* bias = (const float*)d_in[2];
  float* out = (float*)d_out;

  const size_t a_elems = (size_t)M_DIM * K_DIM;
  const size_t w_elems = (size_t)N_DIM * K_DIM;
  const size_t need = (a_elems + w_elems) * sizeof(unsigned short);

  if (ws_size < need) {
    naive_linear<<<dim3(N_DIM / 256, M_DIM), 256, 0, stream>>>(A, W, bias, out);
    return;
  }

  unsigned short* Abf = (unsigned short*)d_ws;
  unsigned short* Wbf = Abf + a_elems;
  const int a4 = (int)(a_elems / 4), tot4 = (int)((a_elems + w_elems) / 4);
  cvt_both<<<2048, 256, 0, stream>>>(A, W, Abf, Wbf, a4, tot4);

  gemm256_8ph<<<(M_DIM / 256) * (N_DIM / 256), 512, 0, stream>>>(
      (const __bf16*)Abf, (const __bf16*)Wbf, bias, out);
}

// Round 6
// 261.654 us; speedup vs baseline: 1.0509x; 1.0509x over previous
//
#include <hip/hip_runtime.h>
#include <hip/hip_bf16.h>
#include <cstdint>
#include <cstddef>

#define M_DIM 8192
#define K_DIM 4096
#define N_DIM 4096

typedef __bf16 bf16x8 __attribute__((ext_vector_type(8)));
typedef float  f32x4  __attribute__((ext_vector_type(4)));

__device__ __forceinline__ unsigned short f32_to_bf16_rne(float f) {
  unsigned int u = __builtin_bit_cast(unsigned int, f);
  u += 0x7FFFu + ((u >> 16) & 1u);
  return (unsigned short)(u >> 16);
}

// Single fused fp32->bf16 conversion for both A and W (one launch).
__global__ void __launch_bounds__(256) cvt_both(const float* __restrict__ A,
                                                const float* __restrict__ W,
                                                unsigned short* __restrict__ Abf,
                                                unsigned short* __restrict__ Wbf,
                                                int a4, int tot4) {
  int i = blockIdx.x * blockDim.x + threadIdx.x;
  int stride = gridDim.x * blockDim.x;
  for (; i < tot4; i += stride) {
    const float4* s = (i < a4) ? &reinterpret_cast<const float4*>(A)[i]
                               : &reinterpret_cast<const float4*>(W)[i - a4];
    ushort4* d = (i < a4) ? &reinterpret_cast<ushort4*>(Abf)[i]
                          : &reinterpret_cast<ushort4*>(Wbf)[i - a4];
    float4 v = *s;
    ushort4 o;
    o.x = f32_to_bf16_rne(v.x);
    o.y = f32_to_bf16_rne(v.y);
    o.z = f32_to_bf16_rne(v.z);
    o.w = f32_to_bf16_rne(v.w);
    *d = o;
  }
}

__device__ __forceinline__ void gload16(const void* g, void* l) {
  __builtin_amdgcn_global_load_lds((const __attribute__((address_space(1))) void*)g,
                                   (__attribute__((address_space(3))) void*)l, 16, 0, 0);
}

// 256x256-tile, BK=64, 8-wave (2Mx4N), 4-WINDOW pipelined GEMM.
//
// ROUND-6 CHANGES (evidence: r5 MfmaUtil 53.7 stuck; barrier-halving was the
// only lever that moved r3->r4; per-window LDS bursts only partially hide):
//  1. 8 phases -> 4 windows/iter. Window = {ds_reads, 2 STAGEs, 32 MFMAs,
//     BAR}. Window MFMA time (~1030 cyc/CU) > worst LDS burst (~640 cyc), so
//     the burst hides fully; barrier count halves.
//  2. 2D XCD grouping: each XCD owns 8bm x 8bn (32 concurrent blocks cover
//     8bm x 4bn); active K-slice per XCD = 12 x 32 KB = 384 KB -> L2-resident
//     (was: 32 A-panels = 64 MB streaming through 4 MB L2 -> FETCH 554 MB).
//
// COLLECTIVE read map for merged windows (LDA8(b,mh) collectively touches
// BOTH A halves since wm spans {0,1}; LDB4(b,nh) touches BOTH B halves since
// wn spans {0..3}):
//   W1 reads buf0.B (all) + buf0.A (part) | W2 reads buf0.A -> buf0.B last
//   read end-W1, buf0.A end-W2 | W3 reads buf1.B + buf1.A | W4 buf1.A ->
//   buf1.B last read end-W3, buf1.A end-W4.
// Stage slots (each >= 1 barrier after its region's last collective read;
// region never read in the stage's own window):
//   W1: b1.A0,b1.A1 <- kb+1  (buf1.A last read prev-iter W4; W1 reads buf0)
//   W2: b0.B0,b0.B1 <- kb+2  (buf0.B done end-W1; W2 reads buf0.A only)
//   W3: b0.A0,b0.A1 <- kb+2  (buf0.A done end-W2; W3 reads buf1 only)
//   W4: b1.B0,b1.B1 <- kb+3  (buf1.B done end-W3; W4 reads buf1.A only)
// Every ds_read in window w feeds an MFMA in w; its counted lgkmcnt wait
// precedes the MFMA which precedes the end-of-window barrier -> reads are
// complete when any wave crosses BAR -> stage issued after BAR is WAR-safe.
//
// vmcnt gates (4 loads/window, in-order retire, per-wave):
//   end-W2 (before W3 reads buf1(kb+1)): outstanding = prevW3(4) + prevW4(4)
//     + W1(4) + W2(4) = 16; need prevW4's b1.B + W1's b1.A = oldest 12
//     -> VM(4). (After prev end-W4's VM(4), <=4 remain + 8 new = <=12; same
//     bound holds with the tighter count.)
//   end-W4 (before next-W1 reads buf0(kb+2)): outstanding <= W2(4) + W3(4)
//     + W4(4) = 12; need W2's b0.B + W3's b0.A = oldest 8 -> VM(4).
//   Youngest gated load issued >= 1 full window (~2000 cyc) before its gate
//   > HBM latency. Never vmcnt(0) in steady state (T4).
__global__ void __launch_bounds__(512, 2)
gemm256_4w(const __bf16* __restrict__ A, const __bf16* __restrict__ W,
           const float* __restrict__ bias, float* __restrict__ out) {
  __shared__ __align__(16) char lds[131072];

  const int tid  = threadIdx.x;
  const int wave = tid >> 6, lane = tid & 63;
  const int wm = wave >> 2, wn = wave & 3;   // 2 x 4 wave grid, each owns 128x64
  const int fr = lane & 15, ko = lane >> 4;

  // 2D XCD grouping (bijective, 512 blocks, 8 XCDs): XCD x = group g owns
  // bm in [ (g&3)*8, +8 ), bn in [ (g>>2)*8, +8 ). First dispatch round
  // (bid 0..255) covers w 0..31 of every group = 8bm x 4bn active set.
  const int swzid = ((blockIdx.x & 7) << 6) + (blockIdx.x >> 3);
  const int g = swzid >> 6, w = swzid & 63;
  const int bm = ((g & 3) << 3) + (w & 7);
  const int bn = ((g >> 2) << 3) + (w >> 3);
  const int brow = bm << 8, bcol = bn << 8;

  // Staging: half-tile = 128 rows x 64 k (16 KiB), 512 threads x 2 gload16.
  // T2 swizzle: LDS 16B-chunk (row, j) holds global k-chunk j ^ (row&7),
  // via pre-swizzled global source + linear (wave-uniform) LDS dest.
  const int r0 = tid >> 3;
  const int jc = (((tid & 7) ^ (r0 & 7)) << 4);
  const char* aSrc = (const char*)A + (size_t)(brow + r0) * (K_DIM * 2) + jc;
  const char* bSrc = (const char*)W + (size_t)(bcol + r0) * (K_DIM * 2) + jc;
  char* dstW = lds + (wave << 10);  // wave-uniform LDS base

#define STAGE(ms, h, bb, kt) do {                                              \
    const char* s_ = ((ms) ? bSrc : aSrc)                                      \
        + (size_t)(h) * (128ull * K_DIM * 2) + (size_t)(kt) * 128;             \
    char* d_ = dstW + (bb) * 65536 + (ms) * 32768 + (h) * 16384;               \
    gload16(s_, d_);                                                           \
    gload16(s_ + 64ull * K_DIM * 2, d_ + 8192);                                \
  } while (0)

  // Hoisted ds_read bases (row&7 == fr&7 for all fragment rows, so the
  // swizzle XOR folds into per-thread-constant low bits).
  const int low0 = (ko << 4) ^ ((fr & 7) << 4);
  const int low1 = low0 ^ 64;
  const char* baA[2][2];  // [bb][k2] -- constant-indexed only
  const char* baB[2][2];
  baA[0][0] = lds + (wm << 14) + (fr << 7) + low0;
  baA[0][1] = lds + (wm << 14) + (fr << 7) + low1;
  baA[1][0] = baA[0][0] + 65536;
  baA[1][1] = baA[0][1] + 65536;
  baB[0][0] = lds + 32768 + (wn << 13) + (fr << 7) + low0;
  baB[0][1] = lds + 32768 + (wn << 13) + (fr << 7) + low1;
  baB[1][0] = baB[0][0] + 65536;
  baB[1][1] = baB[0][1] + 65536;

  bf16x8 a[4][2];   // current m-half fragments (4 m-frags x 2 k-steps)
  bf16x8 b[4][2];   // 4 n-frags x 2 k-steps
  f32x4 acc[8][4] = {};

#define LDA8(bb, mh) do {                                                      \
    _Pragma("unroll") for (int ml = 0; ml < 4; ++ml) {                         \
      a[ml][0] = *(const bf16x8*)(baA[bb][0] + ((mh) << 13) + (ml << 11));     \
      a[ml][1] = *(const bf16x8*)(baA[bb][1] + ((mh) << 13) + (ml << 11)); }   \
  } while (0)

#define LDB4(bb, nh) do {                                                      \
    _Pragma("unroll") for (int nl = 0; nl < 2; ++nl) {                         \
      b[(nh) * 2 + nl][0] = *(const bf16x8*)(baB[bb][0] + ((nh) << 12) + (nl << 11)); \
      b[(nh) * 2 + nl][1] = *(const bf16x8*)(baB[bb][1] + ((nh) << 12) + (nl << 11)); } \
  } while (0)

#define MFMAQ(mh, nh) do {                                                     \
    __builtin_amdgcn_s_setprio(1);                                             \
    _Pragma("unroll") for (int ml = 0; ml < 4; ++ml)                           \
    _Pragma("unroll") for (int nl = 0; nl < 2; ++nl)                           \
    _Pragma("unroll") for (int k2 = 0; k2 < 2; ++k2)                           \
      acc[(mh) * 4 + ml][(nh) * 2 + nl] = __builtin_amdgcn_mfma_f32_16x16x32_bf16( \
          a[ml][k2], b[(nh) * 2 + nl][k2], acc[(mh) * 4 + ml][(nh) * 2 + nl], 0, 0, 0); \
    __builtin_amdgcn_s_setprio(0);                                             \
  } while (0)

#define BAR() __builtin_amdgcn_s_barrier()
#define VM(n) asm volatile("s_waitcnt vmcnt(" #n ")" ::: "memory")

  // Prologue: buf0 <- k0 (all 4 halves), buf1 <- k1 (B0,B1). 12 outstanding;
  // VM(4) -> oldest 8 (= all of buf0 k0) landed. b1.A staged at iter-0 W1.
  STAGE(1, 0, 0, 0);
  STAGE(1, 1, 0, 0);
  STAGE(0, 0, 0, 0);
  STAGE(0, 1, 0, 0);
  STAGE(1, 0, 1, 1);
  STAGE(1, 1, 1, 1);
  VM(4);
  BAR();

  for (int i = 0; i < 31; ++i) {
    const int kb = 2 * i;
    // W1: Q(0,0)+Q(0,1) on buf0 | stage b1.A0,A1 <- kb+1
    LDA8(0, 0); LDB4(0, 0); LDB4(0, 1);
    STAGE(0, 0, 1, kb + 1); STAGE(0, 1, 1, kb + 1);
    MFMAQ(0, 0); MFMAQ(0, 1); BAR();
    // W2: Q(1,1)+Q(1,0) on buf0 | stage b0.B0,B1 <- kb+2 | VM(4): buf1 ready
    LDA8(0, 1);
    STAGE(1, 0, 0, kb + 2); STAGE(1, 1, 0, kb + 2);
    MFMAQ(1, 1); MFMAQ(1, 0); VM(4); BAR();
    // W3: Q(0,0)+Q(0,1) on buf1 | stage b0.A0,A1 <- kb+2
    LDA8(1, 0); LDB4(1, 0); LDB4(1, 1);
    STAGE(0, 0, 0, kb + 2); STAGE(0, 1, 0, kb + 2);
    MFMAQ(0, 0); MFMAQ(0, 1); BAR();
    // W4: Q(1,1)+Q(1,0) on buf1 | stage b1.B0,B1 <- kb+3 | VM(4): buf0 ready
    LDA8(1, 1);
    STAGE(1, 0, 1, kb + 3); STAGE(1, 1, 1, kb + 3);
    MFMAQ(1, 1); MFMAQ(1, 0); VM(4); BAR();
  }

  // Peel (kb=62): stage only b1.A <- k63 at W1; VM(0) at end-W2 drains the
  // 8 outstanding (prev-W4 b1.B: 4, W1 b1.A: 4) = all of buf1 k63.
  LDA8(0, 0); LDB4(0, 0); LDB4(0, 1);
  STAGE(0, 0, 1, 63); STAGE(0, 1, 1, 63);
  MFMAQ(0, 0); MFMAQ(0, 1); BAR();
  LDA8(0, 1);
  MFMAQ(1, 1); MFMAQ(1, 0); VM(0); BAR();
  LDA8(1, 0); LDB4(1, 0); LDB4(1, 1);
  MFMAQ(0, 0); MFMAQ(0, 1); BAR();
  LDA8(1, 1);
  MFMAQ(1, 1); MFMAQ(1, 0);

  // Epilogue: C/D mapping col=lane&15, row=(lane>>4)*4+j (m89-verified), + bias.
  const int oc0 = bcol + (wn << 6) + fr;
  const int or0 = brow + (wm << 7) + (ko << 2);
  float bv[4];
#pragma unroll
  for (int nl = 0; nl < 4; ++nl) bv[nl] = bias[oc0 + nl * 16];
#pragma unroll
  for (int ml = 0; ml < 8; ++ml)
#pragma unroll
    for (int nl = 0; nl < 4; ++nl)
#pragma unroll
      for (int j = 0; j < 4; ++j)
        out[(size_t)(or0 + ml * 16 + j) * N_DIM + (oc0 + nl * 16)] =
            acc[ml][nl][j] + bv[nl];

#undef STAGE
#undef LDA8
#undef LDB4
#undef MFMAQ
#undef BAR
#undef VM
}

// Safety net if d_ws is too small for bf16 copies of A and W: correct but slow.
__global__ void naive_linear(const float* __restrict__ A, const float* __restrict__ W,
                             const float* __restrict__ bias, float* __restrict__ out) {
  int n = blockIdx.y;
  int o = blockIdx.x * 256 + threadIdx.x;
  const float* a = A + (size_t)n * K_DIM;
  const float* w = W + (size_t)o * K_DIM;
  float acc = 0.f;
  for (int k = 0; k < K_DIM; ++k) acc += a[k] * w[k];
  out[(size_t)n * N_DIM + o] = acc + bias[o];
}

extern "C" void kernel_launch(void* const* d_in, const int* in_sizes, int n_in,
                              void* d_out, int out_size, void* d_ws, size_t ws_size,
                              hipStream_t stream) {
  const float* A    = (const float*)d_in[0];
  const float* W    = (const float*)d_in[1];
  const float* bias = (const float*)d_in[2];
  float* out = (float*)d_out;

  const size_t a_elems = (size_t)M_DIM * K_DIM;
  const size_t w_elems = (size_t)N_DIM * K_DIM;
  const size_t need = (a_elems + w_elems) * sizeof(unsigned short);

  if (ws_size < need) {
    naive_linear<<<dim3(N_DIM / 256, M_DIM), 256, 0, stream>>>(A, W, bias, out);
    return;
  }

  unsigned short* Abf = (unsigned short*)d_ws;
  unsigned short* Wbf = Abf + a_elems;
  const int a4 = (int)(a_elems / 4), tot4 = (int)((a_elems + w_elems) / 4);
  cvt_both<<<2048, 256, 0, stream>>>(A, W, Abf, Wbf, a4, tot4);

  gemm256_4w<<<(M_DIM / 256) * (N_DIM / 256), 512, 0, stream>>>(
      (const __bf16*)Abf, (const __bf16*)Wbf, bias, out);
}

// Round 7
// 260.853 us; speedup vs baseline: 1.0541x; 1.0031x over previous
//
#include <hip/hip_runtime.h>
#include <hip/hip_bf16.h>
#include <cstdint>
#include <cstddef>

#define M_DIM 8192
#define K_DIM 4096
#define N_DIM 4096

typedef __bf16 bf16x8 __attribute__((ext_vector_type(8)));
typedef float  f32x4  __attribute__((ext_vector_type(4)));

__device__ __forceinline__ unsigned short f32_to_bf16_rne(float f) {
  unsigned int u = __builtin_bit_cast(unsigned int, f);
  u += 0x7FFFu + ((u >> 16) & 1u);
  return (unsigned short)(u >> 16);
}

// Single fused fp32->bf16 conversion for both A and W (one launch).
__global__ void __launch_bounds__(256) cvt_both(const float* __restrict__ A,
                                                const float* __restrict__ W,
                                                unsigned short* __restrict__ Abf,
                                                unsigned short* __restrict__ Wbf,
                                                int a4, int tot4) {
  int i = blockIdx.x * blockDim.x + threadIdx.x;
  int stride = gridDim.x * blockDim.x;
  for (; i < tot4; i += stride) {
    const float4* s = (i < a4) ? &reinterpret_cast<const float4*>(A)[i]
                               : &reinterpret_cast<const float4*>(W)[i - a4];
    ushort4* d = (i < a4) ? &reinterpret_cast<ushort4*>(Abf)[i]
                          : &reinterpret_cast<ushort4*>(Wbf)[i - a4];
    float4 v = *s;
    ushort4 o;
    o.x = f32_to_bf16_rne(v.x);
    o.y = f32_to_bf16_rne(v.y);
    o.z = f32_to_bf16_rne(v.z);
    o.w = f32_to_bf16_rne(v.w);
    *d = o;
  }
}

__device__ __forceinline__ void gload16(const void* g, void* l) {
  __builtin_amdgcn_global_load_lds((const __attribute__((address_space(1))) void*)g,
                                   (__attribute__((address_space(3))) void*)l, 16, 0, 0);
}

// 256x256-tile, BK=64, 8-wave (2Mx4N), 4-window pipelined GEMM.
//
// ROUND-7 CHANGE (evidence: r6 window = 2087 cyc vs 1242 MFMA-busy; LDS
// demand 96 KB/window ~= 1130 cyc at measured 85-100 B/c service -> front-
// loaded read bursts saturate the LDS queue post-barrier, tail MFMAs wait):
// T19 sched_group_barrier interleave per window, forcing ~{2 ds_read, 4 MFMA}
// clusters so LDS service spreads across the window and overlaps the matrix
// pipe. Read order restructured (LDB4(bb,0) -> LDA8 -> LDB4(bb,1)) so each
// group's MFMAs are dependency-ready:
//   after {b0,b1,a0} (6 reads) -> a0*b0/b1 x k2 = 4 MFMAs; each next a-pair
//   unlocks 4; b2/b3 pairs unlock the nh1 quadrant. Groups sum EXACTLY to
//   window contents (W1/W3: 16 DS + 32 MFMA + 4 VMEM; W2/W4: 8 + 32 + 4).
// SGB only reorders within the barrier-delimited region; counted lgkmcnt
// before each dependent MFMA is still compiler-inserted -> correctness
// unchanged. Stage WAR/visibility audits are window-granular (below),
// unaffected by intra-window reordering.
//
// Collective read map (unchanged from r6): buf0.B last read end-W1, buf0.A
// end-W2, buf1.B end-W3, buf1.A end-W4. Stage slots >=1 barrier after their
// region's last collective read:
//   W1: b1.A <- kb+1 | W2: b0.B <- kb+2 | W3: b0.A <- kb+2 | W4: b1.B <- kb+3
// vmcnt gates: end-W2 VM(4) -> all of buf1(kb+1) landed (oldest 12 of 16);
// end-W4 VM(4) -> all of buf0(kb+2) landed (oldest 8 of 12). Never vmcnt(0)
// in steady state.
__global__ void __launch_bounds__(512, 2)
gemm256_4w(const __bf16* __restrict__ A, const __bf16* __restrict__ W,
           const float* __restrict__ bias, float* __restrict__ out) {
  __shared__ __align__(16) char lds[131072];

  const int tid  = threadIdx.x;
  const int wave = tid >> 6, lane = tid & 63;
  const int wm = wave >> 2, wn = wave & 3;   // 2 x 4 wave grid, each owns 128x64
  const int fr = lane & 15, ko = lane >> 4;

  // 2D XCD grouping (bijective, 512 blocks, 8 XCDs): group g owns bm in
  // [(g&3)*8,+8), bn in [(g>>2)*8,+8); per-K-step active set ~384 KB -> L2.
  const int swzid = ((blockIdx.x & 7) << 6) + (blockIdx.x >> 3);
  const int g = swzid >> 6, w = swzid & 63;
  const int bm = ((g & 3) << 3) + (w & 7);
  const int bn = ((g >> 2) << 3) + (w >> 3);
  const int brow = bm << 8, bcol = bn << 8;

  // Staging: half-tile = 128 rows x 64 k (16 KiB), 512 threads x 2 gload16.
  // T2 swizzle: LDS 16B-chunk (row, j) holds global k-chunk j ^ (row&7),
  // via pre-swizzled global source + linear (wave-uniform) LDS dest.
  const int r0 = tid >> 3;
  const int jc = (((tid & 7) ^ (r0 & 7)) << 4);
  const char* aSrc = (const char*)A + (size_t)(brow + r0) * (K_DIM * 2) + jc;
  const char* bSrc = (const char*)W + (size_t)(bcol + r0) * (K_DIM * 2) + jc;
  char* dstW = lds + (wave << 10);  // wave-uniform LDS base

#define STAGE(ms, h, bb, kt) do {                                              \
    const char* s_ = ((ms) ? bSrc : aSrc)                                      \
        + (size_t)(h) * (128ull * K_DIM * 2) + (size_t)(kt) * 128;             \
    char* d_ = dstW + (bb) * 65536 + (ms) * 32768 + (h) * 16384;               \
    gload16(s_, d_);                                                           \
    gload16(s_ + 64ull * K_DIM * 2, d_ + 8192);                                \
  } while (0)

  // Hoisted ds_read bases (row&7 == fr&7 for all fragment rows, so the
  // swizzle XOR folds into per-thread-constant low bits).
  const int low0 = (ko << 4) ^ ((fr & 7) << 4);
  const int low1 = low0 ^ 64;
  const char* baA[2][2];  // [bb][k2] -- constant-indexed only
  const char* baB[2][2];
  baA[0][0] = lds + (wm << 14) + (fr << 7) + low0;
  baA[0][1] = lds + (wm << 14) + (fr << 7) + low1;
  baA[1][0] = baA[0][0] + 65536;
  baA[1][1] = baA[0][1] + 65536;
  baB[0][0] = lds + 32768 + (wn << 13) + (fr << 7) + low0;
  baB[0][1] = lds + 32768 + (wn << 13) + (fr << 7) + low1;
  baB[1][0] = baB[0][0] + 65536;
  baB[1][1] = baB[0][1] + 65536;

  bf16x8 a[4][2];   // current m-half fragments (4 m-frags x 2 k-steps)
  bf16x8 b[4][2];   // 4 n-frags x 2 k-steps
  f32x4 acc[8][4] = {};

#define LDA8(bb, mh) do {                                                      \
    _Pragma("unroll") for (int ml = 0; ml < 4; ++ml) {                         \
      a[ml][0] = *(const bf16x8*)(baA[bb][0] + ((mh) << 13) + (ml << 11));     \
      a[ml][1] = *(const bf16x8*)(baA[bb][1] + ((mh) << 13) + (ml << 11)); }   \
  } while (0)

#define LDB4(bb, nh) do {                                                      \
    _Pragma("unroll") for (int nl = 0; nl < 2; ++nl) {                         \
      b[(nh) * 2 + nl][0] = *(const bf16x8*)(baB[bb][0] + ((nh) << 12) + (nl << 11)); \
      b[(nh) * 2 + nl][1] = *(const bf16x8*)(baB[bb][1] + ((nh) << 12) + (nl << 11)); } \
  } while (0)

#define MFMAQ(mh, nh) do {                                                     \
    _Pragma("unroll") for (int ml = 0; ml < 4; ++ml)                           \
    _Pragma("unroll") for (int nl = 0; nl < 2; ++nl)                           \
    _Pragma("unroll") for (int k2 = 0; k2 < 2; ++k2)                           \
      acc[(mh) * 4 + ml][(nh) * 2 + nl] = __builtin_amdgcn_mfma_f32_16x16x32_bf16( \
          a[ml][k2], b[(nh) * 2 + nl][k2], acc[(mh) * 4 + ml][(nh) * 2 + nl], 0, 0, 0); \
  } while (0)

#define BAR() __builtin_amdgcn_s_barrier()
#define VM(n) asm volatile("s_waitcnt vmcnt(" #n ")" ::: "memory")
#define SP1() __builtin_amdgcn_s_setprio(1)
#define SP0() __builtin_amdgcn_s_setprio(0)
#define SGB(m, n) __builtin_amdgcn_sched_group_barrier((m), (n), 0)

  // Interleave templates. Masks: MFMA=0x8, VMEM=0x10, DS_READ=0x100 (m137).
  // 16-read window (reads: b0,b1 | a0..a3 | b2,b3; 32 MFMA; 4 gload_lds):
#define ILV16() do {                                                           \
    SGB(0x100, 6); SGB(0x8, 4);   /* b0,b1,a0 -> a0*b0/b1 */                   \
    SGB(0x100, 2); SGB(0x8, 4);   /* a1 -> a1*b0/b1 */                         \
    SGB(0x100, 2); SGB(0x8, 4);   /* a2 */                                     \
    SGB(0x10, 2);                                                              \
    SGB(0x100, 2); SGB(0x8, 4);   /* a3 */                                     \
    SGB(0x10, 2);                                                              \
    SGB(0x100, 2); SGB(0x8, 4);   /* b2 -> *b2 */                              \
    SGB(0x100, 2); SGB(0x8, 12);  /* b3 -> rest */                             \
  } while (0)
  // 8-read window (reads: a0..a3; b-frags persist from previous window):
#define ILV8() do {                                                            \
    SGB(0x100, 2); SGB(0x8, 4);                                                \
    SGB(0x100, 2); SGB(0x8, 4);                                                \
    SGB(0x10, 2);                                                              \
    SGB(0x100, 2); SGB(0x8, 4);                                                \
    SGB(0x10, 2);                                                              \
    SGB(0x100, 2); SGB(0x8, 4);                                                \
    SGB(0x8, 16);                                                              \
  } while (0)

  // Prologue: buf0 <- k0 (all 4 halves), buf1 <- k1 (B0,B1). 12 outstanding;
  // VM(4) -> oldest 8 (= all of buf0 k0) landed. b1.A staged at iter-0 W1.
  STAGE(1, 0, 0, 0);
  STAGE(1, 1, 0, 0);
  STAGE(0, 0, 0, 0);
  STAGE(0, 1, 0, 0);
  STAGE(1, 0, 1, 1);
  STAGE(1, 1, 1, 1);
  VM(4);
  BAR();

  for (int i = 0; i < 31; ++i) {
    const int kb = 2 * i;
    // W1: Q(0,0)+Q(0,1) on buf0 | stage b1.A0,A1 <- kb+1
    SP1();
    LDB4(0, 0); LDA8(0, 0); LDB4(0, 1);
    STAGE(0, 0, 1, kb + 1); STAGE(0, 1, 1, kb + 1);
    MFMAQ(0, 0); MFMAQ(0, 1);
    ILV16();
    SP0(); BAR();
    // W2: Q(1,1)+Q(1,0) on buf0 | stage b0.B0,B1 <- kb+2 | VM(4): buf1 ready
    SP1();
    LDA8(0, 1);
    STAGE(1, 0, 0, kb + 2); STAGE(1, 1, 0, kb + 2);
    MFMAQ(1, 1); MFMAQ(1, 0);
    ILV8();
    SP0(); VM(4); BAR();
    // W3: Q(0,0)+Q(0,1) on buf1 | stage b0.A0,A1 <- kb+2
    SP1();
    LDB4(1, 0); LDA8(1, 0); LDB4(1, 1);
    STAGE(0, 0, 0, kb + 2); STAGE(0, 1, 0, kb + 2);
    MFMAQ(0, 0); MFMAQ(0, 1);
    ILV16();
    SP0(); BAR();
    // W4: Q(1,1)+Q(1,0) on buf1 | stage b1.B0,B1 <- kb+3 | VM(4): buf0 ready
    SP1();
    LDA8(1, 1);
    STAGE(1, 0, 1, kb + 3); STAGE(1, 1, 1, kb + 3);
    MFMAQ(1, 1); MFMAQ(1, 0);
    ILV8();
    SP0(); VM(4); BAR();
  }

  // Peel (kb=62): stage only b1.A <- k63 at W1; VM(0) at end-W2 drains the
  // 8 outstanding (prev-W4 b1.B: 4, W1 b1.A: 4) = all of buf1 k63.
  LDB4(0, 0); LDA8(0, 0); LDB4(0, 1);
  STAGE(0, 0, 1, 63); STAGE(0, 1, 1, 63);
  MFMAQ(0, 0); MFMAQ(0, 1); BAR();
  LDA8(0, 1);
  MFMAQ(1, 1); MFMAQ(1, 0); VM(0); BAR();
  LDB4(1, 0); LDA8(1, 0); LDB4(1, 1);
  MFMAQ(0, 0); MFMAQ(0, 1); BAR();
  LDA8(1, 1);
  MFMAQ(1, 1); MFMAQ(1, 0);

  // Epilogue: C/D mapping col=lane&15, row=(lane>>4)*4+j (m89-verified), + bias.
  const int oc0 = bcol + (wn << 6) + fr;
  const int or0 = brow + (wm << 7) + (ko << 2);
  float bv[4];
#pragma unroll
  for (int nl = 0; nl < 4; ++nl) bv[nl] = bias[oc0 + nl * 16];
#pragma unroll
  for (int ml = 0; ml < 8; ++ml)
#pragma unroll
    for (int nl = 0; nl < 4; ++nl)
#pragma unroll
      for (int j = 0; j < 4; ++j)
        out[(size_t)(or0 + ml * 16 + j) * N_DIM + (oc0 + nl * 16)] =
            acc[ml][nl][j] + bv[nl];

#undef STAGE
#undef LDA8
#undef LDB4
#undef MFMAQ
#undef BAR
#undef VM
#undef SP1
#undef SP0
#undef SGB
#undef ILV16
#undef ILV8
}

// Safety net if d_ws is too small for bf16 copies of A and W: correct but slow.
__global__ void naive_linear(const float* __restrict__ A, const float* __restrict__ W,
                             const float* __restrict__ bias, float* __restrict__ out) {
  int n = blockIdx.y;
  int o = blockIdx.x * 256 + threadIdx.x;
  const float* a = A + (size_t)n * K_DIM;
  const float* w = W + (size_t)o * K_DIM;
  float acc = 0.f;
  for (int k = 0; k < K_DIM; ++k) acc += a[k] * w[k];
  out[(size_t)n * N_DIM + o] = acc + bias[o];
}

extern "C" void kernel_launch(void* const* d_in, const int* in_sizes, int n_in,
                              void* d_out, int out_size, void* d_ws, size_t ws_size,
                              hipStream_t stream) {
  const float* A    = (const float*)d_in[0];
  const float* W    = (const float*)d_in[1];
  const float* bias = (const float*)d_in[2];
  float* out = (float*)d_out;

  const size_t a_elems = (size_t)M_DIM * K_DIM;
  const size_t w_elems = (size_t)N_DIM * K_DIM;
  const size_t need = (a_elems + w_elems) * sizeof(unsigned short);

  if (ws_size < need) {
    naive_linear<<<dim3(N_DIM / 256, M_DIM), 256, 0, stream>>>(A, W, bias, out);
    return;
  }

  unsigned short* Abf = (unsigned short*)d_ws;
  unsigned short* Wbf = Abf + a_elems;
  const int a4 = (int)(a_elems / 4), tot4 = (int)((a_elems + w_elems) / 4);
  cvt_both<<<2048, 256, 0, stream>>>(A, W, Abf, Wbf, a4, tot4);

  gemm256_4w<<<(M_DIM / 256) * (N_DIM / 256), 512, 0, stream>>>(
      (const __bf16*)Abf, (const __bf16*)Wbf, bias, out);
}